// Round 3
// baseline (637.435 us; speedup 1.0000x reference)
//
#include <hip/hip_runtime.h>
#include <math.h>

// BCAM: x1,x2 [8,192,128,128] f32. heads=8, c=24, temperature=0.01.
// R4: all-bf16 MFMA pipeline (conv1/2, norms, scores+softmax, pv, conv5/6/7).
// R6: scores register-direct (no LDS staging, 1024-thr, 4 i-waves x 4 kw),
//     transpose_norms produces o1T/o2T + norms, pv reads A1T from o1T.
// R7: scores k-loop NAMED-REGISTER DOUBLE BUFFER. R6 compiled to VGPR=52 ->
//     zero prefetch, load-use serialized (~2 loads in flight per CU,
//     latency-bound at MfmaUtil 4.6%). Manual 2-step unroll with named
//     qf0/kf0 / qf1/kf1 batches all 9 uint4 loads of step s+1 before the
//     MFMAs of step s -> ~9KB in flight per wave.
// Numerics: bf16 rounding in logits ~0.005 RMS, far below 0.152 threshold.
// pos_bias dropped (per-head scalar, softmax shift-invariant).
// V = UNNORMALIZED tokens (v1=k1 binds before l2norm).

#define N_PIX 16384
#define W_DIM 128
#define C_DIM 192
#define C_PH  24
#define ELEMS 25165824  // 8*192*128*128
#define TINV  100.0f

typedef __bf16 bf16x8 __attribute__((ext_vector_type(8)));
typedef float  f32x4  __attribute__((ext_vector_type(4)));

__device__ __forceinline__ unsigned short f2bf(float f) {
    union { float f; unsigned u; } x; x.f = f;
    unsigned r = x.u + 0x7FFF + ((x.u >> 16) & 1);
    return (unsigned short)(r >> 16);
}
__device__ __forceinline__ float bf2f(unsigned short h) {
    union { unsigned u; float f; } x; x.u = ((unsigned)h) << 16; return x.f;
}
__device__ __forceinline__ unsigned pack2(unsigned short a, unsigned short b) {
    return (unsigned)a | ((unsigned)b << 16);
}

// ---------------------------------------------------------------------------
// conv1x1, f32 input -> bf16 output (conv1/conv2).
// grid (64 p-tiles, 3 m-tiles, 8 b), block 256. Tile 64m x 256p.
// ---------------------------------------------------------------------------
__global__ __launch_bounds__(256)
void conv_f32in(const float* __restrict__ X, const float* __restrict__ Wt,
                const float* __restrict__ bias, unsigned short* __restrict__ Y)
{
    __shared__ unsigned short Ah[64][40];
    __shared__ unsigned short Bh[256][40];

    const int tid = threadIdx.x;
    const int p0 = blockIdx.x << 8;
    const int m0 = blockIdx.y << 6;
    const int b  = blockIdx.z;
    const float* Xb = X + (size_t)b * C_DIM * N_PIX;

    const int wave = tid >> 6, lane = tid & 63;
    const int quad = lane >> 4, l16 = lane & 15;
    const int mw = (wave & 1) << 5;
    const int nw = (wave >> 1) << 7;
    const int koff = quad << 3;

    f32x4 acc[2][8];
    #pragma unroll
    for (int i = 0; i < 2; ++i)
        #pragma unroll
        for (int j = 0; j < 8; ++j) acc[i][j] = (f32x4){0.f, 0.f, 0.f, 0.f};

    for (int k0 = 0; k0 < C_DIM; k0 += 32) {
        // A (weights) 64m x 32k
        #pragma unroll
        for (int i = 0; i < 2; ++i) {
            const int a = (tid << 1) + i;
            const int m = a >> 3, kq = a & 7;
            const float4 v = *(const float4*)(Wt + (size_t)(m0 + m) * C_DIM + k0 + (kq << 2));
            uint2 pk; pk.x = pack2(f2bf(v.x), f2bf(v.y)); pk.y = pack2(f2bf(v.z), f2bf(v.w));
            *(uint2*)(&Ah[m][kq << 2]) = pk;
        }
        // B (pixels) 32k x 256p, 4x4 transpose. kq in low bits -> spread banks.
        #pragma unroll
        for (int r = 0; r < 2; ++r) {
            const int u = tid + (r << 8);
            const int kq = u & 7, p4 = (u >> 3) << 2;
            float4 f[4];
            #pragma unroll
            for (int i = 0; i < 4; ++i)
                f[i] = *(const float4*)(Xb + (size_t)(k0 + (kq << 2) + i) * N_PIX + p0 + p4);
            #pragma unroll
            for (int j = 0; j < 4; ++j) {
                uint2 pk;
                pk.x = pack2(f2bf((&f[0].x)[j]), f2bf((&f[1].x)[j]));
                pk.y = pack2(f2bf((&f[2].x)[j]), f2bf((&f[3].x)[j]));
                *(uint2*)(&Bh[p4 + j][kq << 2]) = pk;
            }
        }
        __syncthreads();

        bf16x8 af[2];
        #pragma unroll
        for (int mf = 0; mf < 2; ++mf)
            af[mf] = *(const bf16x8*)(&Ah[mw + (mf << 4) + l16][koff]);
        #pragma unroll
        for (int nf = 0; nf < 8; ++nf) {
            const bf16x8 bfr = *(const bf16x8*)(&Bh[nw + (nf << 4) + l16][koff]);
            #pragma unroll
            for (int mf = 0; mf < 2; ++mf)
                acc[mf][nf] = __builtin_amdgcn_mfma_f32_16x16x32_bf16(af[mf], bfr, acc[mf][nf], 0, 0, 0);
        }
        __syncthreads();
    }

    const size_t outb = (size_t)b * C_DIM * N_PIX;
    #pragma unroll
    for (int mf = 0; mf < 2; ++mf) {
        #pragma unroll
        for (int r = 0; r < 4; ++r) {
            const int m = m0 + mw + (mf << 4) + (quad << 2) + r;
            const float bm = bias[m];
            const size_t row = outb + (size_t)m * N_PIX;
            #pragma unroll
            for (int nf = 0; nf < 8; ++nf) {
                const int p = p0 + nw + (nf << 4) + l16;
                Y[row + p] = f2bf(acc[mf][nf][r] + bm);
            }
        }
    }
}

// ---------------------------------------------------------------------------
// conv1x1, bf16 input (conv5/6/7). MODE 0: bf16 out; 1: GELU, bf16 out;
// 2: + R1 + R2 (f32), f32 out.
// ---------------------------------------------------------------------------
template<int MODE>
__global__ __launch_bounds__(256)
void conv_b16in(const unsigned short* __restrict__ X, const float* __restrict__ Wt,
                const float* __restrict__ bias, void* __restrict__ Yv,
                const float* __restrict__ R1, const float* __restrict__ R2)
{
    __shared__ unsigned short Ah[64][40];
    __shared__ unsigned short Bh[256][40];

    const int tid = threadIdx.x;
    const int p0 = blockIdx.x << 8;
    const int m0 = blockIdx.y << 6;
    const int b  = blockIdx.z;
    const unsigned short* Xb = X + (size_t)b * C_DIM * N_PIX;

    const int wave = tid >> 6, lane = tid & 63;
    const int quad = lane >> 4, l16 = lane & 15;
    const int mw = (wave & 1) << 5;
    const int nw = (wave >> 1) << 7;
    const int koff = quad << 3;

    f32x4 acc[2][8];
    #pragma unroll
    for (int i = 0; i < 2; ++i)
        #pragma unroll
        for (int j = 0; j < 8; ++j) acc[i][j] = (f32x4){0.f, 0.f, 0.f, 0.f};

    for (int k0 = 0; k0 < C_DIM; k0 += 32) {
        #pragma unroll
        for (int i = 0; i < 2; ++i) {
            const int a = (tid << 1) + i;
            const int m = a >> 3, kq = a & 7;
            const float4 v = *(const float4*)(Wt + (size_t)(m0 + m) * C_DIM + k0 + (kq << 2));
            uint2 pk; pk.x = pack2(f2bf(v.x), f2bf(v.y)); pk.y = pack2(f2bf(v.z), f2bf(v.w));
            *(uint2*)(&Ah[m][kq << 2]) = pk;
        }
        // B: 32k x 256p. Thread: 4 k-rows (kq) x 8 p. Pure ushort transpose.
        {
            const int kq = tid & 7, pg = (tid >> 3) << 3;
            uint4 f[4];
            #pragma unroll
            for (int i = 0; i < 4; ++i)
                f[i] = *(const uint4*)(Xb + (size_t)(k0 + (kq << 2) + i) * N_PIX + p0 + pg);
            #pragma unroll
            for (int j = 0; j < 8; ++j) {
                const unsigned short e0 = ((const unsigned short*)&f[0])[j];
                const unsigned short e1 = ((const unsigned short*)&f[1])[j];
                const unsigned short e2 = ((const unsigned short*)&f[2])[j];
                const unsigned short e3 = ((const unsigned short*)&f[3])[j];
                uint2 pk; pk.x = pack2(e0, e1); pk.y = pack2(e2, e3);
                *(uint2*)(&Bh[pg + j][kq << 2]) = pk;
            }
        }
        __syncthreads();

        bf16x8 af[2];
        #pragma unroll
        for (int mf = 0; mf < 2; ++mf)
            af[mf] = *(const bf16x8*)(&Ah[mw + (mf << 4) + l16][koff]);
        #pragma unroll
        for (int nf = 0; nf < 8; ++nf) {
            const bf16x8 bfr = *(const bf16x8*)(&Bh[nw + (nf << 4) + l16][koff]);
            #pragma unroll
            for (int mf = 0; mf < 2; ++mf)
                acc[mf][nf] = __builtin_amdgcn_mfma_f32_16x16x32_bf16(af[mf], bfr, acc[mf][nf], 0, 0, 0);
        }
        __syncthreads();
    }

    const size_t outb = (size_t)b * C_DIM * N_PIX;
    #pragma unroll
    for (int mf = 0; mf < 2; ++mf) {
        #pragma unroll
        for (int r = 0; r < 4; ++r) {
            const int m = m0 + mw + (mf << 4) + (quad << 2) + r;
            const float bm = bias[m];
            const size_t row = outb + (size_t)m * N_PIX;
            #pragma unroll
            for (int nf = 0; nf < 8; ++nf) {
                const int p = p0 + nw + (nf << 4) + l16;
                float v = acc[mf][nf][r] + bm;
                if (MODE == 1) v = 0.5f * v * (1.0f + erff(v * 0.70710678118654752f));
                if (MODE == 2) {
                    v += R1[row + p] + R2[row + p];
                    ((float*)Yv)[row + p] = v;
                } else {
                    ((unsigned short*)Yv)[row + p] = f2bf(v);
                }
            }
        }
    }
}

// ---------------------------------------------------------------------------
// transpose_norms: per (ch,b,src) 128x128 plane, write plane-transposed copy
// AND accumulate token sum-of-squares. Thread = one 8x8 tile, in-register
// transpose (no LDS for data). norms[src][b][n][dir*128+t] via atomics.
// grid (192 ch, 8 b, 2 src), block 256.
// ---------------------------------------------------------------------------
__global__ __launch_bounds__(256)
void transpose_norms(const unsigned short* __restrict__ o1,
                     const unsigned short* __restrict__ o2,
                     unsigned short* __restrict__ o1T,
                     unsigned short* __restrict__ o2T,
                     float* __restrict__ norms)
{
    __shared__ float hs[128];
    __shared__ float wss[128];

    const int tid = threadIdx.x;
    const int ch  = blockIdx.x;
    const int b   = blockIdx.y;
    const int src = blockIdx.z;
    const int n   = ch / 24;

    const size_t poff = ((size_t)b * C_DIM + ch) * N_PIX;
    const unsigned short* pin = (src ? o2 : o1) + poff;
    unsigned short* pout      = (src ? o2T : o1T) + poff;

    if (tid >= 128) wss[tid - 128] = 0.0f;
    __syncthreads();

    const int h0 = (tid >> 4) << 3;   // 8-row group (exclusive per 16-thread group)
    const int w0 = (tid & 15) << 3;   // 8-col group

    uint4 r[8];
    #pragma unroll
    for (int i = 0; i < 8; ++i)
        r[i] = *(const uint4*)(pin + (size_t)(h0 + i) * W_DIM + w0);

    // transposed store: oT[w0+j][h0..h0+7]
    #pragma unroll
    for (int j = 0; j < 8; ++j) {
        uint4 o;
        unsigned short* op = (unsigned short*)&o;
        #pragma unroll
        for (int i = 0; i < 8; ++i)
            op[i] = ((const unsigned short*)&r[i])[j];
        *(uint4*)(pout + (size_t)(w0 + j) * W_DIM + h0) = o;
    }

    // partial sums of squares
    float hp[8], wp[8];
    #pragma unroll
    for (int i = 0; i < 8; ++i) { hp[i] = 0.0f; wp[i] = 0.0f; }
    #pragma unroll
    for (int i = 0; i < 8; ++i) {
        #pragma unroll
        for (int j = 0; j < 8; ++j) {
            const float v = bf2f(((const unsigned short*)&r[i])[j]);
            hp[i] += v * v;
            wp[j] += v * v;
        }
    }
    // h-rows: the 16 lanes sharing h0 are lanes differing in bits 0..3.
    #pragma unroll
    for (int i = 0; i < 8; ++i) {
        #pragma unroll
        for (int off = 1; off < 16; off <<= 1) hp[i] += __shfl_xor(hp[i], off);
    }
    const int l16 = tid & 15;
    if (l16 < 8) hs[h0 + l16] = hp[l16];  // each group owns its 8 h rows
    // w-cols: lanes sharing w0 within a wave differ in bits 4,5.
    #pragma unroll
    for (int j = 0; j < 8; ++j) {
        wp[j] += __shfl_xor(wp[j], 16);
        wp[j] += __shfl_xor(wp[j], 32);
    }
    if ((tid & 63) < 16) {
        #pragma unroll
        for (int j = 0; j < 8; ++j) atomicAdd(&wss[w0 + j], wp[j]);
    }
    __syncthreads();

    float* np_ = norms + ((size_t)(src * 8 + b) * 8 + n) * 256;
    if (tid < 128) atomicAdd(&np_[tid], hs[tid]);
    else           atomicAdd(&np_[tid], wss[tid - 128]);
}

// ---------------------------------------------------------------------------
// Fused scores+softmax: S = Qbf.Kbf^T (full K=3072), scale 100*rq*rk, row
// softmax, pre-scale by gate weight, write P bf16.
// R6: register-direct fragments, no LDS staging, no k-loop barriers.
// R7: named-register double-buffered prefetch (9 uint4 in flight per wave).
// grid (2 i-tiles, 64 bn, 2 dir), block 1024 = 16 waves (4 i-waves x 4 kw).
// ---------------------------------------------------------------------------
__global__ __launch_bounds__(1024)
void scores_softmax(const unsigned short* __restrict__ o1,
                    const unsigned short* __restrict__ o2,
                    const unsigned short* __restrict__ o1T,
                    const unsigned short* __restrict__ o2T,
                    const float* __restrict__ norms, const float* __restrict__ gate,
                    unsigned short* __restrict__ P)
{
    __shared__ float Sred[3][4][16][132];
    __shared__ float rqv[64], rkv[128];

    const int tid = threadIdx.x;
    const int i0  = blockIdx.x << 6;
    const int bn  = blockIdx.y;
    const int dir = blockIdx.z;
    const int b = bn >> 3, n = bn & 7;

    const size_t base = (size_t)b * C_DIM * N_PIX + (size_t)n * C_PH * N_PIX;
    // dir0: tokens = h-rows (natural planes). dir1: tokens = w-rows (transposed).
    const unsigned short* Qb = (dir == 0 ? o2 : o1T) + base;
    const unsigned short* Kb = (dir == 0 ? o1 : o2T) + base;

    const int qsrc = (dir == 0) ? 1 : 0;
    const float* qn_g = norms + ((size_t)(qsrc * 8 + b) * 8 + n) * 256 + dir * 128;
    const float* kn_g = norms + ((size_t)((1 - qsrc) * 8 + b) * 8 + n) * 256 + dir * 128;

    if (tid < 64)        rqv[tid]      = TINV * rsqrtf(fmaxf(qn_g[i0 + tid], 1e-24f));
    else if (tid < 192)  rkv[tid - 64] = rsqrtf(fmaxf(kn_g[tid - 64], 1e-24f));

    const int wave = tid >> 6, lane = tid & 63;
    const int iw = wave & 3;    // i-wave: rows i0 + iw*16 .. +15
    const int kw = wave >> 2;   // K-split group: k = kw*768 .. +768
    const int quad = lane >> 4, l16 = lane & 15;

    // per-lane row bases (token-row major, k contiguous within plane row)
    const unsigned short* rq = Qb + (size_t)(i0 + (iw << 4) + l16) * W_DIM + (quad << 3);
    const unsigned short* rk = Kb + (size_t)l16 * W_DIM + (quad << 3);

    f32x4 acc[8];
    #pragma unroll
    for (int j = 0; j < 8; ++j) acc[j] = (f32x4){0.f, 0.f, 0.f, 0.f};

    const int ks0 = kw * 24;

#define SS_ADDR(ks) ((size_t)((ks) >> 2) * N_PIX + (size_t)(((ks) & 3) << 5))
#define SS_LOAD(qf, kf, ks) do { \
        const size_t off_ = SS_ADDR(ks); \
        qf = *(const uint4*)(rq + off_); \
        _Pragma("unroll") \
        for (int nf_ = 0; nf_ < 8; ++nf_) \
            kf[nf_] = *(const uint4*)(rk + off_ + (nf_ << 11)); \
    } while (0)
#define SS_MFMA(qf, kf) do { \
        const bf16x8 a_ = *(const bf16x8*)&qf; \
        _Pragma("unroll") \
        for (int nf_ = 0; nf_ < 8; ++nf_) \
            acc[nf_] = __builtin_amdgcn_mfma_f32_16x16x32_bf16(a_, *(const bf16x8*)&kf[nf_], acc[nf_], 0, 0, 0); \
    } while (0)

    uint4 qf0, kf0[8], qf1, kf1[8];
    SS_LOAD(qf0, kf0, ks0);
    #pragma unroll 1
    for (int s = 0; s < 24; s += 2) {
        SS_LOAD(qf1, kf1, ks0 + s + 1);           // prefetch s+1 (9 loads batched)
        SS_MFMA(qf0, kf0);                        // compute s
        if (s + 2 < 24) SS_LOAD(qf0, kf0, ks0 + s + 2);  // prefetch s+2
        SS_MFMA(qf1, kf1);                        // compute s+1
    }
#undef SS_ADDR
#undef SS_LOAD
#undef SS_MFMA

    if (kw != 0) {
        float* dst = &Sred[kw - 1][iw][0][0];
        #pragma unroll
        for (int nf = 0; nf < 8; ++nf)
            #pragma unroll
            for (int r = 0; r < 4; ++r)
                dst[(size_t)((quad << 2) + r) * 132 + (nf << 4) + l16] = acc[nf][r];
    }
    __syncthreads();
    if (kw != 0) return;

    // kw==0 waves: combine partials, softmax, store P.
    const float g = 1.0f / (1.0f + __expf(-gate[0]));
    const float gs = (dir == 0) ? g : (1.0f - g);
    unsigned short* Pg = P + (((size_t)dir * 64 + bn) << 14);

    #pragma unroll
    for (int r = 0; r < 4; ++r) {
        const int row16 = (quad << 2) + r;
        const int i_loc = (iw << 4) + row16;
        const float rqs = rqv[i_loc];
        float v[8], m = -1e30f;
        #pragma unroll
        for (int nf = 0; nf < 8; ++nf) {
            const int col = (nf << 4) + l16;
            float sv = acc[nf][r]
                     + Sred[0][iw][row16][col]
                     + Sred[1][iw][row16][col]
                     + Sred[2][iw][row16][col];
            v[nf] = sv * rqs * rkv[col];
            m = fmaxf(m, v[nf]);
        }
        #pragma unroll
        for (int off = 1; off < 16; off <<= 1) m = fmaxf(m, __shfl_xor(m, off));
        float s = 0.0f;
        #pragma unroll
        for (int nf = 0; nf < 8; ++nf) { v[nf] = __expf(v[nf] - m); s += v[nf]; }
        #pragma unroll
        for (int off = 1; off < 16; off <<= 1) s += __shfl_xor(s, off);
        const float inv = gs / s;
        const size_t rowo = (size_t)(i0 + i_loc) * 128;
        #pragma unroll
        for (int nf = 0; nf < 8; ++nf)
            Pg[rowo + (nf << 4) + l16] = f2bf(v[nf] * inv);
    }
}

// ---------------------------------------------------------------------------
// pv: per (ch, bn) plane, F = P1g@A1 + A2@P2g^T + g*rq1[h]*A2 + (1-g)*rq2[w]*A1.
// All inputs bf16 (P carries gate factors). A1^T tile read directly from o1T.
// grid (24 ch, 64 bn), block 256.
// ---------------------------------------------------------------------------
__global__ __launch_bounds__(256)
void pv_mfma(const unsigned short* __restrict__ o1, const unsigned short* __restrict__ o2,
             const unsigned short* __restrict__ o1T,
             const unsigned short* __restrict__ P, const float* __restrict__ norms,
             const float* __restrict__ gate, unsigned short* __restrict__ fusion)
{
    __shared__ unsigned short P1s[128][40];
    __shared__ unsigned short A2s[128][40];
    __shared__ unsigned short P2s[128][40];
    __shared__ unsigned short A1Ts[128][40];
    __shared__ float rqs[256];

    const int tid = threadIdx.x;
    const int ch  = blockIdx.x;
    const int bn  = blockIdx.y;
    const int b = bn >> 3, n = bn & 7;

    const size_t pbase = (size_t)b * C_DIM * N_PIX + ((size_t)n * C_PH + ch) * N_PIX;
    const unsigned short* A1  = o1 + pbase;
    const unsigned short* A2  = o2 + pbase;
    const unsigned short* A1T = o1T + pbase;
    const unsigned short* P1 = P + ((size_t)bn << 14);
    const unsigned short* P2 = P + ((size_t)(64 + bn) << 14);
    unsigned short* Fp = fusion + pbase;

    const float g = 1.0f / (1.0f + __expf(-gate[0]));
    if (tid < 128)
        rqs[tid] = g * rsqrtf(fmaxf(norms[(((size_t)8 + b) * 8 + n) * 256 + tid], 1e-24f));
    else
        rqs[tid] = (1.0f - g) * rsqrtf(fmaxf(norms[(((size_t)b) * 8 + n) * 256 + 128 + (tid - 128)], 1e-24f));

    const int wave = tid >> 6, lane = tid & 63;
    const int quad = lane >> 4, l16 = lane & 15;
    const int i0w = wave << 5;
    const int koff = quad << 3;

    f32x4 acc[2][8];
    #pragma unroll
    for (int i = 0; i < 2; ++i)
        #pragma unroll
        for (int j = 0; j < 8; ++j) acc[i][j] = (f32x4){0.f, 0.f, 0.f, 0.f};

    for (int k0 = 0; k0 < 128; k0 += 32) {
        // all four tiles are natural row-major uint4 copies now
        #pragma unroll
        for (int r = 0; r < 2; ++r) {
            const int u = tid + (r << 8);
            const int row = u >> 2, k8 = u & 3;
            const size_t go = (size_t)row * 128 + k0 + (k8 << 3);
            *(uint4*)(&P1s[row][k8 << 3])  = *(const uint4*)(P1 + go);
            *(uint4*)(&A2s[row][k8 << 3])  = *(const uint4*)(A2 + go);
            *(uint4*)(&P2s[row][k8 << 3])  = *(const uint4*)(P2 + go);
            *(uint4*)(&A1Ts[row][k8 << 3]) = *(const uint4*)(A1T + go);
        }
        __syncthreads();

        bf16x8 p1f[2], a2f[2];
        #pragma unroll
        for (int mf = 0; mf < 2; ++mf) {
            p1f[mf] = *(const bf16x8*)(&P1s[i0w + (mf << 4) + l16][koff]);
            a2f[mf] = *(const bf16x8*)(&A2s[i0w + (mf << 4) + l16][koff]);
        }
        #pragma unroll
        for (int nf = 0; nf < 8; ++nf) {
            const bf16x8 b1 = *(const bf16x8*)(&A1Ts[(nf << 4) + l16][koff]);
            const bf16x8 b2 = *(const bf16x8*)(&P2s[(nf << 4) + l16][koff]);
            #pragma unroll
            for (int mf = 0; mf < 2; ++mf) {
                acc[mf][nf] = __builtin_amdgcn_mfma_f32_16x16x32_bf16(p1f[mf], b1, acc[mf][nf], 0, 0, 0);
                acc[mf][nf] = __builtin_amdgcn_mfma_f32_16x16x32_bf16(a2f[mf], b2, acc[mf][nf], 0, 0, 0);
            }
        }
        __syncthreads();
    }

    #pragma unroll
    for (int mf = 0; mf < 2; ++mf) {
        #pragma unroll
        for (int r = 0; r < 4; ++r) {
            const int i = i0w + (mf << 4) + (quad << 2) + r;
            const float c1 = rqs[i];
            #pragma unroll
            for (int nf = 0; nf < 8; ++nf) {
                const int w = (nf << 4) + l16;
                const size_t o = (size_t)i * 128 + w;
                const float F = acc[mf][nf][r] + c1 * bf2f(A2[o]) + rqs[128 + w] * bf2f(A1[o]);
                Fp[o] = f2bf(F);
            }
        }
    }
}

// ---------------------------------------------------------------------------
extern "C" void kernel_launch(void* const* d_in, const int* in_sizes, int n_in,
                              void* d_out, int out_size, void* d_ws, size_t ws_size,
                              hipStream_t stream)
{
    (void)in_sizes; (void)n_in; (void)out_size; (void)ws_size;
    const float* x1     = (const float*)d_in[0];
    const float* x2     = (const float*)d_in[1];
    const float* W_proj = (const float*)d_in[2];
    const float* b_proj = (const float*)d_in[3];
    const float* gate   = (const float*)d_in[4];
    // d_in[5], d_in[6]: pos_bias_h/w — per-head scalars, cancel in softmax.
    const float* W_m1   = (const float*)d_in[7];
    const float* b_m1   = (const float*)d_in[8];
    const float* W_m2   = (const float*)d_in[9];
    const float* b_m2   = (const float*)d_in[10];

    unsigned short* o1    = (unsigned short*)d_ws;       // out1 bf16
    unsigned short* o2    = o1 + ELEMS;                  // out2 bf16
    float*          norms = (float*)(o2 + ELEMS);        // 32768 f32
    unsigned short* Pbuf  = (unsigned short*)(norms + 32768);  // 2*64*16384 bf16

    // d_out aliasing: [o2T (dead before pv) -> fusion][o1T (dead before conv7)]
    unsigned short* o2T    = (unsigned short*)d_out;
    unsigned short* fusion = o2T;
    unsigned short* o1T    = o2T + ELEMS;

    const dim3 cgrid(64, 3, 8);
    conv_f32in<<<cgrid, 256, 0, stream>>>(x1, W_proj, b_proj, o1);
    conv_f32in<<<cgrid, 256, 0, stream>>>(x2, W_proj, b_proj, o2);

    hipMemsetAsync(norms, 0, 32768 * sizeof(float), stream);
    transpose_norms<<<dim3(192, 8, 2), 256, 0, stream>>>(o1, o2, o1T, o2T, norms);

    scores_softmax<<<dim3(2, 64, 2), 1024, 0, stream>>>(o1, o2, o1T, o2T, norms, gate, Pbuf);
    pv_mfma<<<dim3(24, 64), 256, 0, stream>>>(o1, o2, o1T, Pbuf, norms, gate, fusion);

    conv_b16in<0><<<cgrid, 256, 0, stream>>>(fusion, W_proj, b_proj, o1, nullptr, nullptr);
    conv_b16in<1><<<cgrid, 256, 0, stream>>>(o1, W_m1, b_m1, o2, nullptr, nullptr);
    conv_b16in<2><<<cgrid, 256, 0, stream>>>(o2, W_m2, b_m2, d_out, x1, x2);
}

// Round 4
// 636.856 us; speedup vs baseline: 1.0009x; 1.0009x over previous
//
#include <hip/hip_runtime.h>
#include <math.h>

// BCAM: x1,x2 [8,192,128,128] f32. heads=8, c=24, temperature=0.01.
// R4: all-bf16 MFMA pipeline (conv1/2, norms, scores+softmax, pv, conv5/6/7).
// R6: scores register-direct (no LDS staging, 1024-thr, 4 i-waves x 4 kw),
//     transpose_norms produces o1T/o2T + norms, pv reads A1T from o1T.
// R7 FAILED: compiler ignored named-register dbuf (VGPR stayed 60, loads
//     re-serialized, dur unchanged).
// R8: INLINE-ASM pipelined loads. global_load_dwordx4 via asm volatile with
//     counted `s_waitcnt vmcnt(9)` + sched_barrier(0) (rule #18) -> compiler
//     cannot sink the prefetch; 18 loads (9KB/wave) stay in flight across
//     each MFMA cluster. Grid reordered to (bn, i0, dir) so the two i0
//     blocks sharing a K panel land on the same XCD (64 apart = same XCD).
// Numerics: bf16 rounding in logits ~0.005 RMS, far below 0.152 threshold.
// pos_bias dropped (per-head scalar, softmax shift-invariant).
// V = UNNORMALIZED tokens (v1=k1 binds before l2norm).

#define N_PIX 16384
#define W_DIM 128
#define C_DIM 192
#define C_PH  24
#define ELEMS 25165824  // 8*192*128*128
#define TINV  100.0f

typedef __bf16 bf16x8 __attribute__((ext_vector_type(8)));
typedef float  f32x4  __attribute__((ext_vector_type(4)));

__device__ __forceinline__ unsigned short f2bf(float f) {
    union { float f; unsigned u; } x; x.f = f;
    unsigned r = x.u + 0x7FFF + ((x.u >> 16) & 1);
    return (unsigned short)(r >> 16);
}
__device__ __forceinline__ float bf2f(unsigned short h) {
    union { unsigned u; float f; } x; x.u = ((unsigned)h) << 16; return x.f;
}
__device__ __forceinline__ unsigned pack2(unsigned short a, unsigned short b) {
    return (unsigned)a | ((unsigned)b << 16);
}

// ---------------------------------------------------------------------------
// conv1x1, f32 input -> bf16 output (conv1/conv2).
// grid (64 p-tiles, 3 m-tiles, 8 b), block 256. Tile 64m x 256p.
// ---------------------------------------------------------------------------
__global__ __launch_bounds__(256)
void conv_f32in(const float* __restrict__ X, const float* __restrict__ Wt,
                const float* __restrict__ bias, unsigned short* __restrict__ Y)
{
    __shared__ unsigned short Ah[64][40];
    __shared__ unsigned short Bh[256][40];

    const int tid = threadIdx.x;
    const int p0 = blockIdx.x << 8;
    const int m0 = blockIdx.y << 6;
    const int b  = blockIdx.z;
    const float* Xb = X + (size_t)b * C_DIM * N_PIX;

    const int wave = tid >> 6, lane = tid & 63;
    const int quad = lane >> 4, l16 = lane & 15;
    const int mw = (wave & 1) << 5;
    const int nw = (wave >> 1) << 7;
    const int koff = quad << 3;

    f32x4 acc[2][8];
    #pragma unroll
    for (int i = 0; i < 2; ++i)
        #pragma unroll
        for (int j = 0; j < 8; ++j) acc[i][j] = (f32x4){0.f, 0.f, 0.f, 0.f};

    for (int k0 = 0; k0 < C_DIM; k0 += 32) {
        // A (weights) 64m x 32k
        #pragma unroll
        for (int i = 0; i < 2; ++i) {
            const int a = (tid << 1) + i;
            const int m = a >> 3, kq = a & 7;
            const float4 v = *(const float4*)(Wt + (size_t)(m0 + m) * C_DIM + k0 + (kq << 2));
            uint2 pk; pk.x = pack2(f2bf(v.x), f2bf(v.y)); pk.y = pack2(f2bf(v.z), f2bf(v.w));
            *(uint2*)(&Ah[m][kq << 2]) = pk;
        }
        // B (pixels) 32k x 256p, 4x4 transpose. kq in low bits -> spread banks.
        #pragma unroll
        for (int r = 0; r < 2; ++r) {
            const int u = tid + (r << 8);
            const int kq = u & 7, p4 = (u >> 3) << 2;
            float4 f[4];
            #pragma unroll
            for (int i = 0; i < 4; ++i)
                f[i] = *(const float4*)(Xb + (size_t)(k0 + (kq << 2) + i) * N_PIX + p0 + p4);
            #pragma unroll
            for (int j = 0; j < 4; ++j) {
                uint2 pk;
                pk.x = pack2(f2bf((&f[0].x)[j]), f2bf((&f[1].x)[j]));
                pk.y = pack2(f2bf((&f[2].x)[j]), f2bf((&f[3].x)[j]));
                *(uint2*)(&Bh[p4 + j][kq << 2]) = pk;
            }
        }
        __syncthreads();

        bf16x8 af[2];
        #pragma unroll
        for (int mf = 0; mf < 2; ++mf)
            af[mf] = *(const bf16x8*)(&Ah[mw + (mf << 4) + l16][koff]);
        #pragma unroll
        for (int nf = 0; nf < 8; ++nf) {
            const bf16x8 bfr = *(const bf16x8*)(&Bh[nw + (nf << 4) + l16][koff]);
            #pragma unroll
            for (int mf = 0; mf < 2; ++mf)
                acc[mf][nf] = __builtin_amdgcn_mfma_f32_16x16x32_bf16(af[mf], bfr, acc[mf][nf], 0, 0, 0);
        }
        __syncthreads();
    }

    const size_t outb = (size_t)b * C_DIM * N_PIX;
    #pragma unroll
    for (int mf = 0; mf < 2; ++mf) {
        #pragma unroll
        for (int r = 0; r < 4; ++r) {
            const int m = m0 + mw + (mf << 4) + (quad << 2) + r;
            const float bm = bias[m];
            const size_t row = outb + (size_t)m * N_PIX;
            #pragma unroll
            for (int nf = 0; nf < 8; ++nf) {
                const int p = p0 + nw + (nf << 4) + l16;
                Y[row + p] = f2bf(acc[mf][nf][r] + bm);
            }
        }
    }
}

// ---------------------------------------------------------------------------
// conv1x1, bf16 input (conv5/6/7). MODE 0: bf16 out; 1: GELU, bf16 out;
// 2: + R1 + R2 (f32), f32 out.
// ---------------------------------------------------------------------------
template<int MODE>
__global__ __launch_bounds__(256)
void conv_b16in(const unsigned short* __restrict__ X, const float* __restrict__ Wt,
                const float* __restrict__ bias, void* __restrict__ Yv,
                const float* __restrict__ R1, const float* __restrict__ R2)
{
    __shared__ unsigned short Ah[64][40];
    __shared__ unsigned short Bh[256][40];

    const int tid = threadIdx.x;
    const int p0 = blockIdx.x << 8;
    const int m0 = blockIdx.y << 6;
    const int b  = blockIdx.z;
    const unsigned short* Xb = X + (size_t)b * C_DIM * N_PIX;

    const int wave = tid >> 6, lane = tid & 63;
    const int quad = lane >> 4, l16 = lane & 15;
    const int mw = (wave & 1) << 5;
    const int nw = (wave >> 1) << 7;
    const int koff = quad << 3;

    f32x4 acc[2][8];
    #pragma unroll
    for (int i = 0; i < 2; ++i)
        #pragma unroll
        for (int j = 0; j < 8; ++j) acc[i][j] = (f32x4){0.f, 0.f, 0.f, 0.f};

    for (int k0 = 0; k0 < C_DIM; k0 += 32) {
        #pragma unroll
        for (int i = 0; i < 2; ++i) {
            const int a = (tid << 1) + i;
            const int m = a >> 3, kq = a & 7;
            const float4 v = *(const float4*)(Wt + (size_t)(m0 + m) * C_DIM + k0 + (kq << 2));
            uint2 pk; pk.x = pack2(f2bf(v.x), f2bf(v.y)); pk.y = pack2(f2bf(v.z), f2bf(v.w));
            *(uint2*)(&Ah[m][kq << 2]) = pk;
        }
        // B: 32k x 256p. Thread: 4 k-rows (kq) x 8 p. Pure ushort transpose.
        {
            const int kq = tid & 7, pg = (tid >> 3) << 3;
            uint4 f[4];
            #pragma unroll
            for (int i = 0; i < 4; ++i)
                f[i] = *(const uint4*)(Xb + (size_t)(k0 + (kq << 2) + i) * N_PIX + p0 + pg);
            #pragma unroll
            for (int j = 0; j < 8; ++j) {
                const unsigned short e0 = ((const unsigned short*)&f[0])[j];
                const unsigned short e1 = ((const unsigned short*)&f[1])[j];
                const unsigned short e2 = ((const unsigned short*)&f[2])[j];
                const unsigned short e3 = ((const unsigned short*)&f[3])[j];
                uint2 pk; pk.x = pack2(e0, e1); pk.y = pack2(e2, e3);
                *(uint2*)(&Bh[pg + j][kq << 2]) = pk;
            }
        }
        __syncthreads();

        bf16x8 af[2];
        #pragma unroll
        for (int mf = 0; mf < 2; ++mf)
            af[mf] = *(const bf16x8*)(&Ah[mw + (mf << 4) + l16][koff]);
        #pragma unroll
        for (int nf = 0; nf < 8; ++nf) {
            const bf16x8 bfr = *(const bf16x8*)(&Bh[nw + (nf << 4) + l16][koff]);
            #pragma unroll
            for (int mf = 0; mf < 2; ++mf)
                acc[mf][nf] = __builtin_amdgcn_mfma_f32_16x16x32_bf16(af[mf], bfr, acc[mf][nf], 0, 0, 0);
        }
        __syncthreads();
    }

    const size_t outb = (size_t)b * C_DIM * N_PIX;
    #pragma unroll
    for (int mf = 0; mf < 2; ++mf) {
        #pragma unroll
        for (int r = 0; r < 4; ++r) {
            const int m = m0 + mw + (mf << 4) + (quad << 2) + r;
            const float bm = bias[m];
            const size_t row = outb + (size_t)m * N_PIX;
            #pragma unroll
            for (int nf = 0; nf < 8; ++nf) {
                const int p = p0 + nw + (nf << 4) + l16;
                float v = acc[mf][nf][r] + bm;
                if (MODE == 1) v = 0.5f * v * (1.0f + erff(v * 0.70710678118654752f));
                if (MODE == 2) {
                    v += R1[row + p] + R2[row + p];
                    ((float*)Yv)[row + p] = v;
                } else {
                    ((unsigned short*)Yv)[row + p] = f2bf(v);
                }
            }
        }
    }
}

// ---------------------------------------------------------------------------
// transpose_norms: per (ch,b,src) 128x128 plane, write plane-transposed copy
// AND accumulate token sum-of-squares. Thread = one 8x8 tile, in-register
// transpose (no LDS for data). norms[src][b][n][dir*128+t] via atomics.
// grid (192 ch, 8 b, 2 src), block 256.
// ---------------------------------------------------------------------------
__global__ __launch_bounds__(256)
void transpose_norms(const unsigned short* __restrict__ o1,
                     const unsigned short* __restrict__ o2,
                     unsigned short* __restrict__ o1T,
                     unsigned short* __restrict__ o2T,
                     float* __restrict__ norms)
{
    __shared__ float hs[128];
    __shared__ float wss[128];

    const int tid = threadIdx.x;
    const int ch  = blockIdx.x;
    const int b   = blockIdx.y;
    const int src = blockIdx.z;
    const int n   = ch / 24;

    const size_t poff = ((size_t)b * C_DIM + ch) * N_PIX;
    const unsigned short* pin = (src ? o2 : o1) + poff;
    unsigned short* pout      = (src ? o2T : o1T) + poff;

    if (tid >= 128) wss[tid - 128] = 0.0f;
    __syncthreads();

    const int h0 = (tid >> 4) << 3;   // 8-row group (exclusive per 16-thread group)
    const int w0 = (tid & 15) << 3;   // 8-col group

    uint4 r[8];
    #pragma unroll
    for (int i = 0; i < 8; ++i)
        r[i] = *(const uint4*)(pin + (size_t)(h0 + i) * W_DIM + w0);

    // transposed store: oT[w0+j][h0..h0+7]
    #pragma unroll
    for (int j = 0; j < 8; ++j) {
        uint4 o;
        unsigned short* op = (unsigned short*)&o;
        #pragma unroll
        for (int i = 0; i < 8; ++i)
            op[i] = ((const unsigned short*)&r[i])[j];
        *(uint4*)(pout + (size_t)(w0 + j) * W_DIM + h0) = o;
    }

    // partial sums of squares
    float hp[8], wp[8];
    #pragma unroll
    for (int i = 0; i < 8; ++i) { hp[i] = 0.0f; wp[i] = 0.0f; }
    #pragma unroll
    for (int i = 0; i < 8; ++i) {
        #pragma unroll
        for (int j = 0; j < 8; ++j) {
            const float v = bf2f(((const unsigned short*)&r[i])[j]);
            hp[i] += v * v;
            wp[j] += v * v;
        }
    }
    // h-rows: the 16 lanes sharing h0 are lanes differing in bits 0..3.
    #pragma unroll
    for (int i = 0; i < 8; ++i) {
        #pragma unroll
        for (int off = 1; off < 16; off <<= 1) hp[i] += __shfl_xor(hp[i], off);
    }
    const int l16 = tid & 15;
    if (l16 < 8) hs[h0 + l16] = hp[l16];  // each group owns its 8 h rows
    // w-cols: lanes sharing w0 within a wave differ in bits 4,5.
    #pragma unroll
    for (int j = 0; j < 8; ++j) {
        wp[j] += __shfl_xor(wp[j], 16);
        wp[j] += __shfl_xor(wp[j], 32);
    }
    if ((tid & 63) < 16) {
        #pragma unroll
        for (int j = 0; j < 8; ++j) atomicAdd(&wss[w0 + j], wp[j]);
    }
    __syncthreads();

    float* np_ = norms + ((size_t)(src * 8 + b) * 8 + n) * 256;
    if (tid < 128) atomicAdd(&np_[tid], hs[tid]);
    else           atomicAdd(&np_[tid], wss[tid - 128]);
}

// ---------------------------------------------------------------------------
// Fused scores+softmax: S = Qbf.Kbf^T (full K=3072), scale 100*rq*rk, row
// softmax, pre-scale by gate weight, write P bf16.
// R8: inline-asm pipelined register-direct loads (counted vmcnt(9), depth-2
// named buffers the compiler cannot sink). grid (64 bn, 2 i0, 2 dir), block
// 1024 = 16 waves (4 i-waves x 4 kw). i0-pairs 64 linear-ids apart -> same
// XCD -> shared K panel in L2.
// ---------------------------------------------------------------------------
__global__ __launch_bounds__(1024)
void scores_softmax(const unsigned short* __restrict__ o1,
                    const unsigned short* __restrict__ o2,
                    const unsigned short* __restrict__ o1T,
                    const unsigned short* __restrict__ o2T,
                    const float* __restrict__ norms, const float* __restrict__ gate,
                    unsigned short* __restrict__ P)
{
    __shared__ float Sred[3][4][16][132];
    __shared__ float rqv[64], rkv[128];

    const int tid = threadIdx.x;
    const int bn  = blockIdx.x;
    const int i0  = blockIdx.y << 6;
    const int dir = blockIdx.z;
    const int b = bn >> 3, n = bn & 7;

    const size_t base = (size_t)b * C_DIM * N_PIX + (size_t)n * C_PH * N_PIX;
    // dir0: tokens = h-rows (natural planes). dir1: tokens = w-rows (transposed).
    const unsigned short* Qb = (dir == 0 ? o2 : o1T) + base;
    const unsigned short* Kb = (dir == 0 ? o1 : o2T) + base;

    const int qsrc = (dir == 0) ? 1 : 0;
    const float* qn_g = norms + ((size_t)(qsrc * 8 + b) * 8 + n) * 256 + dir * 128;
    const float* kn_g = norms + ((size_t)((1 - qsrc) * 8 + b) * 8 + n) * 256 + dir * 128;

    if (tid < 64)        rqv[tid]      = TINV * rsqrtf(fmaxf(qn_g[i0 + tid], 1e-24f));
    else if (tid < 192)  rkv[tid - 64] = rsqrtf(fmaxf(kn_g[tid - 64], 1e-24f));

    const int wave = tid >> 6, lane = tid & 63;
    const int iw = wave & 3;    // i-wave: rows i0 + iw*16 .. +15
    const int kw = wave >> 2;   // K-split group: k = kw*768 .. +768
    const int quad = lane >> 4, l16 = lane & 15;

    // per-lane row bases (token-row major, k contiguous within plane row)
    const unsigned short* rq = Qb + (size_t)(i0 + (iw << 4) + l16) * W_DIM + (quad << 3);
    const unsigned short* rk = Kb + (size_t)l16 * W_DIM + (quad << 3);

    f32x4 acc[8];
    #pragma unroll
    for (int j = 0; j < 8; ++j) acc[j] = (f32x4){0.f, 0.f, 0.f, 0.f};

    const int ks0 = kw * 24;

#define SS_ADDR(ks) ((size_t)((ks) >> 2) * N_PIX + (size_t)(((ks) & 3) << 5))
// asm loads: compiler cannot sink/serialize these (R7 failure mode).
#define SS_LOADA(qf, kf, ks) do { \
        const size_t off_ = SS_ADDR(ks); \
        const unsigned short* qp_ = rq + off_; \
        asm volatile("global_load_dwordx4 %0, %1, off" : "=v"(qf) : "v"(qp_)); \
        _Pragma("unroll") \
        for (int nf_ = 0; nf_ < 8; ++nf_) { \
            const unsigned short* kp_ = rk + off_ + (nf_ << 11); \
            asm volatile("global_load_dwordx4 %0, %1, off" : "=v"(kf[nf_]) : "v"(kp_)); \
        } \
    } while (0)
#define SS_WAIT(n) do { \
        asm volatile("s_waitcnt vmcnt(" #n ")" ::: "memory"); \
        __builtin_amdgcn_sched_barrier(0); \
    } while (0)
#define SS_MFMA(qf, kf) do { \
        const bf16x8 a_ = *(const bf16x8*)&qf; \
        _Pragma("unroll") \
        for (int nf_ = 0; nf_ < 8; ++nf_) \
            acc[nf_] = __builtin_amdgcn_mfma_f32_16x16x32_bf16(a_, *(const bf16x8*)&kf[nf_], acc[nf_], 0, 0, 0); \
    } while (0)

    uint4 qf0, kf0[8], qf1, kf1[8];
    SS_LOADA(qf0, kf0, ks0);                      // 9 outstanding
    #pragma unroll 1
    for (int s = 0; s < 22; s += 2) {
        SS_LOADA(qf1, kf1, ks0 + s + 1);          // 18 outstanding
        SS_WAIT(9);                               // buf0 ready
        SS_MFMA(qf0, kf0);
        SS_LOADA(qf0, kf0, ks0 + s + 2);          // 18 outstanding
        SS_WAIT(9);                               // buf1 ready
        SS_MFMA(qf1, kf1);
    }
    SS_LOADA(qf1, kf1, ks0 + 23);
    SS_WAIT(9);
    SS_MFMA(qf0, kf0);
    SS_WAIT(0);
    SS_MFMA(qf1, kf1);
#undef SS_ADDR
#undef SS_LOADA
#undef SS_WAIT
#undef SS_MFMA

    if (kw != 0) {
        float* dst = &Sred[kw - 1][iw][0][0];
        #pragma unroll
        for (int nf = 0; nf < 8; ++nf)
            #pragma unroll
            for (int r = 0; r < 4; ++r)
                dst[(size_t)((quad << 2) + r) * 132 + (nf << 4) + l16] = acc[nf][r];
    }
    __syncthreads();
    if (kw != 0) return;

    // kw==0 waves: combine partials, softmax, store P.
    const float g = 1.0f / (1.0f + __expf(-gate[0]));
    const float gs = (dir == 0) ? g : (1.0f - g);
    unsigned short* Pg = P + (((size_t)dir * 64 + bn) << 14);

    #pragma unroll
    for (int r = 0; r < 4; ++r) {
        const int row16 = (quad << 2) + r;
        const int i_loc = (iw << 4) + row16;
        const float rqs = rqv[i_loc];
        float v[8], m = -1e30f;
        #pragma unroll
        for (int nf = 0; nf < 8; ++nf) {
            const int col = (nf << 4) + l16;
            float sv = acc[nf][r]
                     + Sred[0][iw][row16][col]
                     + Sred[1][iw][row16][col]
                     + Sred[2][iw][row16][col];
            v[nf] = sv * rqs * rkv[col];
            m = fmaxf(m, v[nf]);
        }
        #pragma unroll
        for (int off = 1; off < 16; off <<= 1) m = fmaxf(m, __shfl_xor(m, off));
        float s = 0.0f;
        #pragma unroll
        for (int nf = 0; nf < 8; ++nf) { v[nf] = __expf(v[nf] - m); s += v[nf]; }
        #pragma unroll
        for (int off = 1; off < 16; off <<= 1) s += __shfl_xor(s, off);
        const float inv = gs / s;
        const size_t rowo = (size_t)(i0 + i_loc) * 128;
        #pragma unroll
        for (int nf = 0; nf < 8; ++nf)
            Pg[rowo + (nf << 4) + l16] = f2bf(v[nf] * inv);
    }
}

// ---------------------------------------------------------------------------
// pv: per (ch, bn) plane, F = P1g@A1 + A2@P2g^T + g*rq1[h]*A2 + (1-g)*rq2[w]*A1.
// All inputs bf16 (P carries gate factors). A1^T tile read directly from o1T.
// grid (24 ch, 64 bn), block 256.
// ---------------------------------------------------------------------------
__global__ __launch_bounds__(256)
void pv_mfma(const unsigned short* __restrict__ o1, const unsigned short* __restrict__ o2,
             const unsigned short* __restrict__ o1T,
             const unsigned short* __restrict__ P, const float* __restrict__ norms,
             const float* __restrict__ gate, unsigned short* __restrict__ fusion)
{
    __shared__ unsigned short P1s[128][40];
    __shared__ unsigned short A2s[128][40];
    __shared__ unsigned short P2s[128][40];
    __shared__ unsigned short A1Ts[128][40];
    __shared__ float rqs[256];

    const int tid = threadIdx.x;
    const int ch  = blockIdx.x;
    const int bn  = blockIdx.y;
    const int b = bn >> 3, n = bn & 7;

    const size_t pbase = (size_t)b * C_DIM * N_PIX + ((size_t)n * C_PH + ch) * N_PIX;
    const unsigned short* A1  = o1 + pbase;
    const unsigned short* A2  = o2 + pbase;
    const unsigned short* A1T = o1T + pbase;
    const unsigned short* P1 = P + ((size_t)bn << 14);
    const unsigned short* P2 = P + ((size_t)(64 + bn) << 14);
    unsigned short* Fp = fusion + pbase;

    const float g = 1.0f / (1.0f + __expf(-gate[0]));
    if (tid < 128)
        rqs[tid] = g * rsqrtf(fmaxf(norms[(((size_t)8 + b) * 8 + n) * 256 + tid], 1e-24f));
    else
        rqs[tid] = (1.0f - g) * rsqrtf(fmaxf(norms[(((size_t)b) * 8 + n) * 256 + 128 + (tid - 128)], 1e-24f));

    const int wave = tid >> 6, lane = tid & 63;
    const int quad = lane >> 4, l16 = lane & 15;
    const int i0w = wave << 5;
    const int koff = quad << 3;

    f32x4 acc[2][8];
    #pragma unroll
    for (int i = 0; i < 2; ++i)
        #pragma unroll
        for (int j = 0; j < 8; ++j) acc[i][j] = (f32x4){0.f, 0.f, 0.f, 0.f};

    for (int k0 = 0; k0 < 128; k0 += 32) {
        // all four tiles are natural row-major uint4 copies now
        #pragma unroll
        for (int r = 0; r < 2; ++r) {
            const int u = tid + (r << 8);
            const int row = u >> 2, k8 = u & 3;
            const size_t go = (size_t)row * 128 + k0 + (k8 << 3);
            *(uint4*)(&P1s[row][k8 << 3])  = *(const uint4*)(P1 + go);
            *(uint4*)(&A2s[row][k8 << 3])  = *(const uint4*)(A2 + go);
            *(uint4*)(&P2s[row][k8 << 3])  = *(const uint4*)(P2 + go);
            *(uint4*)(&A1Ts[row][k8 << 3]) = *(const uint4*)(A1T + go);
        }
        __syncthreads();

        bf16x8 p1f[2], a2f[2];
        #pragma unroll
        for (int mf = 0; mf < 2; ++mf) {
            p1f[mf] = *(const bf16x8*)(&P1s[i0w + (mf << 4) + l16][koff]);
            a2f[mf] = *(const bf16x8*)(&A2s[i0w + (mf << 4) + l16][koff]);
        }
        #pragma unroll
        for (int nf = 0; nf < 8; ++nf) {
            const bf16x8 b1 = *(const bf16x8*)(&A1Ts[(nf << 4) + l16][koff]);
            const bf16x8 b2 = *(const bf16x8*)(&P2s[(nf << 4) + l16][koff]);
            #pragma unroll
            for (int mf = 0; mf < 2; ++mf) {
                acc[mf][nf] = __builtin_amdgcn_mfma_f32_16x16x32_bf16(p1f[mf], b1, acc[mf][nf], 0, 0, 0);
                acc[mf][nf] = __builtin_amdgcn_mfma_f32_16x16x32_bf16(a2f[mf], b2, acc[mf][nf], 0, 0, 0);
            }
        }
        __syncthreads();
    }

    #pragma unroll
    for (int mf = 0; mf < 2; ++mf) {
        #pragma unroll
        for (int r = 0; r < 4; ++r) {
            const int i = i0w + (mf << 4) + (quad << 2) + r;
            const float c1 = rqs[i];
            #pragma unroll
            for (int nf = 0; nf < 8; ++nf) {
                const int w = (nf << 4) + l16;
                const size_t o = (size_t)i * 128 + w;
                const float F = acc[mf][nf][r] + c1 * bf2f(A2[o]) + rqs[128 + w] * bf2f(A1[o]);
                Fp[o] = f2bf(F);
            }
        }
    }
}

// ---------------------------------------------------------------------------
extern "C" void kernel_launch(void* const* d_in, const int* in_sizes, int n_in,
                              void* d_out, int out_size, void* d_ws, size_t ws_size,
                              hipStream_t stream)
{
    (void)in_sizes; (void)n_in; (void)out_size; (void)ws_size;
    const float* x1     = (const float*)d_in[0];
    const float* x2     = (const float*)d_in[1];
    const float* W_proj = (const float*)d_in[2];
    const float* b_proj = (const float*)d_in[3];
    const float* gate   = (const float*)d_in[4];
    // d_in[5], d_in[6]: pos_bias_h/w — per-head scalars, cancel in softmax.
    const float* W_m1   = (const float*)d_in[7];
    const float* b_m1   = (const float*)d_in[8];
    const float* W_m2   = (const float*)d_in[9];
    const float* b_m2   = (const float*)d_in[10];

    unsigned short* o1    = (unsigned short*)d_ws;       // out1 bf16
    unsigned short* o2    = o1 + ELEMS;                  // out2 bf16
    float*          norms = (float*)(o2 + ELEMS);        // 32768 f32
    unsigned short* Pbuf  = (unsigned short*)(norms + 32768);  // 2*64*16384 bf16

    // d_out aliasing: [o2T (dead before pv) -> fusion][o1T (dead before conv7)]
    unsigned short* o2T    = (unsigned short*)d_out;
    unsigned short* fusion = o2T;
    unsigned short* o1T    = o2T + ELEMS;

    const dim3 cgrid(64, 3, 8);
    conv_f32in<<<cgrid, 256, 0, stream>>>(x1, W_proj, b_proj, o1);
    conv_f32in<<<cgrid, 256, 0, stream>>>(x2, W_proj, b_proj, o2);

    hipMemsetAsync(norms, 0, 32768 * sizeof(float), stream);
    transpose_norms<<<dim3(192, 8, 2), 256, 0, stream>>>(o1, o2, o1T, o2T, norms);

    scores_softmax<<<dim3(64, 2, 2), 1024, 0, stream>>>(o1, o2, o1T, o2T, norms, gate, Pbuf);
    pv_mfma<<<dim3(24, 64), 256, 0, stream>>>(o1, o2, o1T, Pbuf, norms, gate, fusion);

    conv_b16in<0><<<cgrid, 256, 0, stream>>>(fusion, W_proj, b_proj, o1, nullptr, nullptr);
    conv_b16in<1><<<cgrid, 256, 0, stream>>>(o1, W_m1, b_m1, o2, nullptr, nullptr);
    conv_b16in<2><<<cgrid, 256, 0, stream>>>(o2, W_m2, b_m2, d_out, x1, x2);
}

// Round 5
// 580.522 us; speedup vs baseline: 1.0980x; 1.0970x over previous
//
#include <hip/hip_runtime.h>
#include <math.h>

// BCAM: x1,x2 [8,192,128,128] f32. heads=8, c=24, temperature=0.01.
// R4: all-bf16 MFMA pipeline (conv1/2, norms, scores+softmax, pv, conv5/6/7).
// R6: transpose_norms produces o1T/o2T + norms; pv reads A1T from o1T.
// R7/R8 FAILED: register-direct scores stuck at 104us across three schedules
//   -> per-instruction wall, not latency. Loads were 16-lane column reads
//   (4 lanes/64B-line, 16 lines over 4KB): ~64cy/instr TA cost x 3456 instrs
//   = the 104us. Schedule-insensitive => divergence-throughput-bound.
// R9: scores restaged through LDS with LANE-CONTIGUOUS 1KB loads:
//   k-loop = 24 channel-steps (k-span 128). Q tile (64 rows) / K tile (128
//   rows) are contiguous 16KB/32KB -> 48 coalesced 1KB loads/step/block
//   (1152 vs 3456, ~4x cheaper each). Fragments via padded LDS (272B stride,
//   2-way = free). T14 pipeline: asm loads for s+1 live in 12 uint4 regs
//   across compute(s); vmcnt(0)+sched_barrier before ds_write (rule #18).
//   No kw split -> no Sred; LDS 53KB -> 2 blocks/CU.
// Numerics: bf16 rounding in logits ~0.005 RMS, far below 0.152 threshold.
// pos_bias dropped (per-head scalar, softmax shift-invariant).
// V = UNNORMALIZED tokens (v1=k1 binds before l2norm).

#define N_PIX 16384
#define W_DIM 128
#define C_DIM 192
#define C_PH  24
#define ELEMS 25165824  // 8*192*128*128
#define TINV  100.0f

typedef __bf16 bf16x8 __attribute__((ext_vector_type(8)));
typedef float  f32x4  __attribute__((ext_vector_type(4)));

__device__ __forceinline__ unsigned short f2bf(float f) {
    union { float f; unsigned u; } x; x.f = f;
    unsigned r = x.u + 0x7FFF + ((x.u >> 16) & 1);
    return (unsigned short)(r >> 16);
}
__device__ __forceinline__ float bf2f(unsigned short h) {
    union { unsigned u; float f; } x; x.u = ((unsigned)h) << 16; return x.f;
}
__device__ __forceinline__ unsigned pack2(unsigned short a, unsigned short b) {
    return (unsigned)a | ((unsigned)b << 16);
}

// ---------------------------------------------------------------------------
// conv1x1, f32 input -> bf16 output (conv1/conv2).
// grid (64 p-tiles, 3 m-tiles, 8 b), block 256. Tile 64m x 256p.
// ---------------------------------------------------------------------------
__global__ __launch_bounds__(256)
void conv_f32in(const float* __restrict__ X, const float* __restrict__ Wt,
                const float* __restrict__ bias, unsigned short* __restrict__ Y)
{
    __shared__ unsigned short Ah[64][40];
    __shared__ unsigned short Bh[256][40];

    const int tid = threadIdx.x;
    const int p0 = blockIdx.x << 8;
    const int m0 = blockIdx.y << 6;
    const int b  = blockIdx.z;
    const float* Xb = X + (size_t)b * C_DIM * N_PIX;

    const int wave = tid >> 6, lane = tid & 63;
    const int quad = lane >> 4, l16 = lane & 15;
    const int mw = (wave & 1) << 5;
    const int nw = (wave >> 1) << 7;
    const int koff = quad << 3;

    f32x4 acc[2][8];
    #pragma unroll
    for (int i = 0; i < 2; ++i)
        #pragma unroll
        for (int j = 0; j < 8; ++j) acc[i][j] = (f32x4){0.f, 0.f, 0.f, 0.f};

    for (int k0 = 0; k0 < C_DIM; k0 += 32) {
        // A (weights) 64m x 32k
        #pragma unroll
        for (int i = 0; i < 2; ++i) {
            const int a = (tid << 1) + i;
            const int m = a >> 3, kq = a & 7;
            const float4 v = *(const float4*)(Wt + (size_t)(m0 + m) * C_DIM + k0 + (kq << 2));
            uint2 pk; pk.x = pack2(f2bf(v.x), f2bf(v.y)); pk.y = pack2(f2bf(v.z), f2bf(v.w));
            *(uint2*)(&Ah[m][kq << 2]) = pk;
        }
        // B (pixels) 32k x 256p, 4x4 transpose. kq in low bits -> spread banks.
        #pragma unroll
        for (int r = 0; r < 2; ++r) {
            const int u = tid + (r << 8);
            const int kq = u & 7, p4 = (u >> 3) << 2;
            float4 f[4];
            #pragma unroll
            for (int i = 0; i < 4; ++i)
                f[i] = *(const float4*)(Xb + (size_t)(k0 + (kq << 2) + i) * N_PIX + p0 + p4);
            #pragma unroll
            for (int j = 0; j < 4; ++j) {
                uint2 pk;
                pk.x = pack2(f2bf((&f[0].x)[j]), f2bf((&f[1].x)[j]));
                pk.y = pack2(f2bf((&f[2].x)[j]), f2bf((&f[3].x)[j]));
                *(uint2*)(&Bh[p4 + j][kq << 2]) = pk;
            }
        }
        __syncthreads();

        bf16x8 af[2];
        #pragma unroll
        for (int mf = 0; mf < 2; ++mf)
            af[mf] = *(const bf16x8*)(&Ah[mw + (mf << 4) + l16][koff]);
        #pragma unroll
        for (int nf = 0; nf < 8; ++nf) {
            const bf16x8 bfr = *(const bf16x8*)(&Bh[nw + (nf << 4) + l16][koff]);
            #pragma unroll
            for (int mf = 0; mf < 2; ++mf)
                acc[mf][nf] = __builtin_amdgcn_mfma_f32_16x16x32_bf16(af[mf], bfr, acc[mf][nf], 0, 0, 0);
        }
        __syncthreads();
    }

    const size_t outb = (size_t)b * C_DIM * N_PIX;
    #pragma unroll
    for (int mf = 0; mf < 2; ++mf) {
        #pragma unroll
        for (int r = 0; r < 4; ++r) {
            const int m = m0 + mw + (mf << 4) + (quad << 2) + r;
            const float bm = bias[m];
            const size_t row = outb + (size_t)m * N_PIX;
            #pragma unroll
            for (int nf = 0; nf < 8; ++nf) {
                const int p = p0 + nw + (nf << 4) + l16;
                Y[row + p] = f2bf(acc[mf][nf][r] + bm);
            }
        }
    }
}

// ---------------------------------------------------------------------------
// conv1x1, bf16 input (conv5/6/7). MODE 0: bf16 out; 1: GELU, bf16 out;
// 2: + R1 + R2 (f32), f32 out.
// ---------------------------------------------------------------------------
template<int MODE>
__global__ __launch_bounds__(256)
void conv_b16in(const unsigned short* __restrict__ X, const float* __restrict__ Wt,
                const float* __restrict__ bias, void* __restrict__ Yv,
                const float* __restrict__ R1, const float* __restrict__ R2)
{
    __shared__ unsigned short Ah[64][40];
    __shared__ unsigned short Bh[256][40];

    const int tid = threadIdx.x;
    const int p0 = blockIdx.x << 8;
    const int m0 = blockIdx.y << 6;
    const int b  = blockIdx.z;
    const unsigned short* Xb = X + (size_t)b * C_DIM * N_PIX;

    const int wave = tid >> 6, lane = tid & 63;
    const int quad = lane >> 4, l16 = lane & 15;
    const int mw = (wave & 1) << 5;
    const int nw = (wave >> 1) << 7;
    const int koff = quad << 3;

    f32x4 acc[2][8];
    #pragma unroll
    for (int i = 0; i < 2; ++i)
        #pragma unroll
        for (int j = 0; j < 8; ++j) acc[i][j] = (f32x4){0.f, 0.f, 0.f, 0.f};

    for (int k0 = 0; k0 < C_DIM; k0 += 32) {
        #pragma unroll
        for (int i = 0; i < 2; ++i) {
            const int a = (tid << 1) + i;
            const int m = a >> 3, kq = a & 7;
            const float4 v = *(const float4*)(Wt + (size_t)(m0 + m) * C_DIM + k0 + (kq << 2));
            uint2 pk; pk.x = pack2(f2bf(v.x), f2bf(v.y)); pk.y = pack2(f2bf(v.z), f2bf(v.w));
            *(uint2*)(&Ah[m][kq << 2]) = pk;
        }
        // B: 32k x 256p. Thread: 4 k-rows (kq) x 8 p. Pure ushort transpose.
        {
            const int kq = tid & 7, pg = (tid >> 3) << 3;
            uint4 f[4];
            #pragma unroll
            for (int i = 0; i < 4; ++i)
                f[i] = *(const uint4*)(Xb + (size_t)(k0 + (kq << 2) + i) * N_PIX + p0 + pg);
            #pragma unroll
            for (int j = 0; j < 8; ++j) {
                const unsigned short e0 = ((const unsigned short*)&f[0])[j];
                const unsigned short e1 = ((const unsigned short*)&f[1])[j];
                const unsigned short e2 = ((const unsigned short*)&f[2])[j];
                const unsigned short e3 = ((const unsigned short*)&f[3])[j];
                uint2 pk; pk.x = pack2(e0, e1); pk.y = pack2(e2, e3);
                *(uint2*)(&Bh[pg + j][kq << 2]) = pk;
            }
        }
        __syncthreads();

        bf16x8 af[2];
        #pragma unroll
        for (int mf = 0; mf < 2; ++mf)
            af[mf] = *(const bf16x8*)(&Ah[mw + (mf << 4) + l16][koff]);
        #pragma unroll
        for (int nf = 0; nf < 8; ++nf) {
            const bf16x8 bfr = *(const bf16x8*)(&Bh[nw + (nf << 4) + l16][koff]);
            #pragma unroll
            for (int mf = 0; mf < 2; ++mf)
                acc[mf][nf] = __builtin_amdgcn_mfma_f32_16x16x32_bf16(af[mf], bfr, acc[mf][nf], 0, 0, 0);
        }
        __syncthreads();
    }

    const size_t outb = (size_t)b * C_DIM * N_PIX;
    #pragma unroll
    for (int mf = 0; mf < 2; ++mf) {
        #pragma unroll
        for (int r = 0; r < 4; ++r) {
            const int m = m0 + mw + (mf << 4) + (quad << 2) + r;
            const float bm = bias[m];
            const size_t row = outb + (size_t)m * N_PIX;
            #pragma unroll
            for (int nf = 0; nf < 8; ++nf) {
                const int p = p0 + nw + (nf << 4) + l16;
                float v = acc[mf][nf][r] + bm;
                if (MODE == 1) v = 0.5f * v * (1.0f + erff(v * 0.70710678118654752f));
                if (MODE == 2) {
                    v += R1[row + p] + R2[row + p];
                    ((float*)Yv)[row + p] = v;
                } else {
                    ((unsigned short*)Yv)[row + p] = f2bf(v);
                }
            }
        }
    }
}

// ---------------------------------------------------------------------------
// transpose_norms: per (ch,b,src) 128x128 plane, write plane-transposed copy
// AND accumulate token sum-of-squares. Thread = one 8x8 tile, in-register
// transpose (no LDS for data). norms[src][b][n][dir*128+t] via atomics.
// grid (192 ch, 8 b, 2 src), block 256.
// ---------------------------------------------------------------------------
__global__ __launch_bounds__(256)
void transpose_norms(const unsigned short* __restrict__ o1,
                     const unsigned short* __restrict__ o2,
                     unsigned short* __restrict__ o1T,
                     unsigned short* __restrict__ o2T,
                     float* __restrict__ norms)
{
    __shared__ float hs[128];
    __shared__ float wss[128];

    const int tid = threadIdx.x;
    const int ch  = blockIdx.x;
    const int b   = blockIdx.y;
    const int src = blockIdx.z;
    const int n   = ch / 24;

    const size_t poff = ((size_t)b * C_DIM + ch) * N_PIX;
    const unsigned short* pin = (src ? o2 : o1) + poff;
    unsigned short* pout      = (src ? o2T : o1T) + poff;

    if (tid >= 128) wss[tid - 128] = 0.0f;
    __syncthreads();

    const int h0 = (tid >> 4) << 3;   // 8-row group (exclusive per 16-thread group)
    const int w0 = (tid & 15) << 3;   // 8-col group

    uint4 r[8];
    #pragma unroll
    for (int i = 0; i < 8; ++i)
        r[i] = *(const uint4*)(pin + (size_t)(h0 + i) * W_DIM + w0);

    // transposed store: oT[w0+j][h0..h0+7]
    #pragma unroll
    for (int j = 0; j < 8; ++j) {
        uint4 o;
        unsigned short* op = (unsigned short*)&o;
        #pragma unroll
        for (int i = 0; i < 8; ++i)
            op[i] = ((const unsigned short*)&r[i])[j];
        *(uint4*)(pout + (size_t)(w0 + j) * W_DIM + h0) = o;
    }

    // partial sums of squares
    float hp[8], wp[8];
    #pragma unroll
    for (int i = 0; i < 8; ++i) { hp[i] = 0.0f; wp[i] = 0.0f; }
    #pragma unroll
    for (int i = 0; i < 8; ++i) {
        #pragma unroll
        for (int j = 0; j < 8; ++j) {
            const float v = bf2f(((const unsigned short*)&r[i])[j]);
            hp[i] += v * v;
            wp[j] += v * v;
        }
    }
    // h-rows: the 16 lanes sharing h0 are lanes differing in bits 0..3.
    #pragma unroll
    for (int i = 0; i < 8; ++i) {
        #pragma unroll
        for (int off = 1; off < 16; off <<= 1) hp[i] += __shfl_xor(hp[i], off);
    }
    const int l16 = tid & 15;
    if (l16 < 8) hs[h0 + l16] = hp[l16];  // each group owns its 8 h rows
    // w-cols: lanes sharing w0 within a wave differ in bits 4,5.
    #pragma unroll
    for (int j = 0; j < 8; ++j) {
        wp[j] += __shfl_xor(wp[j], 16);
        wp[j] += __shfl_xor(wp[j], 32);
    }
    if ((tid & 63) < 16) {
        #pragma unroll
        for (int j = 0; j < 8; ++j) atomicAdd(&wss[w0 + j], wp[j]);
    }
    __syncthreads();

    float* np_ = norms + ((size_t)(src * 8 + b) * 8 + n) * 256;
    if (tid < 128) atomicAdd(&np_[tid], hs[tid]);
    else           atomicAdd(&np_[tid], wss[tid - 128]);
}

// ---------------------------------------------------------------------------
// Fused scores+softmax: S = Qbf.Kbf^T (full K=3072), scale 100*rq*rk, row
// softmax, pre-scale by gate weight, write P bf16.
// R9: 24 channel-macro-steps (k-span 128). Lane-contiguous 1KB staging loads
// (Q 16KB + K 32KB contiguous per step) -> 12 asm loads/thread held in regs
// across compute (T14); vmcnt(0)+sched_barrier then ds_write to padded LDS
// (272B row stride). Each wave owns 16 i-rows with full K -> direct softmax.
// grid (64 bn, 2 i0, 2 dir), block 256 (4 waves).
// ---------------------------------------------------------------------------
#define SS_KBASE 17408            // 64*272
#define SS_STRIDE 272

__global__ __launch_bounds__(256)
void scores_softmax(const unsigned short* __restrict__ o1,
                    const unsigned short* __restrict__ o2,
                    const unsigned short* __restrict__ o1T,
                    const unsigned short* __restrict__ o2T,
                    const float* __restrict__ norms, const float* __restrict__ gate,
                    unsigned short* __restrict__ P)
{
    __shared__ __align__(16) unsigned char SMEM[SS_KBASE + 128 * SS_STRIDE];
    __shared__ float rqv[64], rkv[128];

    const int tid = threadIdx.x;
    const int bn  = blockIdx.x;
    const int i0  = blockIdx.y << 6;
    const int dir = blockIdx.z;
    const int b = bn >> 3, n = bn & 7;

    const size_t base = (size_t)b * C_DIM * N_PIX + (size_t)n * C_PH * N_PIX;
    // dir0: tokens = h-rows (natural planes). dir1: tokens = w-rows (transposed).
    const unsigned short* Qb = (dir == 0 ? o2 : o1T) + base;
    const unsigned short* Kb = (dir == 0 ? o1 : o2T) + base;

    const int qsrc = (dir == 0) ? 1 : 0;
    const float* qn_g = norms + ((size_t)(qsrc * 8 + b) * 8 + n) * 256 + dir * 128;
    const float* kn_g = norms + ((size_t)((1 - qsrc) * 8 + b) * 8 + n) * 256 + dir * 128;

    if (tid < 64)        rqv[tid]      = TINV * rsqrtf(fmaxf(qn_g[i0 + tid], 1e-24f));
    else if (tid < 192)  rkv[tid - 64] = rsqrtf(fmaxf(kn_g[tid - 64], 1e-24f));

    const int wave = tid >> 6, lane = tid & 63;
    const int quad = lane >> 4, l16 = lane & 15;

    // staging geometry: per step, Q tile = 16KB contiguous (64 rows from i0),
    // K tile = 32KB contiguous (full plane). thread loads 4 Q + 8 K 16B-chunks,
    // instr j covers chunk j*256+tid -> lane-contiguous 1KB per wave-instr.
    const char* qsrc0 = (const char*)(Qb + (size_t)i0 * W_DIM) + tid * 16;
    const char* ksrc0 = (const char*)Kb + tid * 16;
    const int l_base = ((tid >> 4) * SS_STRIDE) + ((tid & 15) << 4);

    f32x4 acc[8];
    #pragma unroll
    for (int j = 0; j < 8; ++j) acc[j] = (f32x4){0.f, 0.f, 0.f, 0.f};

    uint4 rg[12];

#define SS_ISSUE(sch) do { \
        const char* qs_ = qsrc0 + (size_t)(sch) * 32768; \
        const char* ks_ = ksrc0 + (size_t)(sch) * 32768; \
        _Pragma("unroll") \
        for (int j_ = 0; j_ < 4; ++j_) { \
            const char* p_ = qs_ + j_ * 4096; \
            asm volatile("global_load_dwordx4 %0, %1, off" : "=v"(rg[j_]) : "v"(p_)); \
        } \
        _Pragma("unroll") \
        for (int j_ = 0; j_ < 8; ++j_) { \
            const char* p_ = ks_ + j_ * 4096; \
            asm volatile("global_load_dwordx4 %0, %1, off" : "=v"(rg[4 + j_]) : "v"(p_)); \
        } \
        __builtin_amdgcn_sched_barrier(0); \
    } while (0)

#define SS_WRITE() do { \
        asm volatile("s_waitcnt vmcnt(0)" ::: "memory"); \
        __builtin_amdgcn_sched_barrier(0); \
        _Pragma("unroll") \
        for (int j_ = 0; j_ < 4; ++j_) \
            *(uint4*)(SMEM + j_ * 4352 + l_base) = rg[j_]; \
        _Pragma("unroll") \
        for (int j_ = 0; j_ < 8; ++j_) \
            *(uint4*)(SMEM + SS_KBASE + j_ * 4352 + l_base) = rg[4 + j_]; \
    } while (0)

#define SS_COMPUTE() do { \
        _Pragma("unroll") \
        for (int ks_ = 0; ks_ < 4; ++ks_) { \
            const int ko_ = ks_ * 64 + quad * 16; \
            const bf16x8 a_ = *(const bf16x8*)(SMEM + ((wave << 4) + l16) * SS_STRIDE + ko_); \
            _Pragma("unroll") \
            for (int nf_ = 0; nf_ < 8; ++nf_) { \
                const bf16x8 b_ = *(const bf16x8*)(SMEM + SS_KBASE + ((nf_ << 4) + l16) * SS_STRIDE + ko_); \
                acc[nf_] = __builtin_amdgcn_mfma_f32_16x16x32_bf16(a_, b_, acc[nf_], 0, 0, 0); \
            } \
        } \
    } while (0)

    SS_ISSUE(0);
    SS_WRITE();
    __syncthreads();
    #pragma unroll 1
    for (int s = 0; s < 24; ++s) {
        if (s + 1 < 24) SS_ISSUE(s + 1);
        SS_COMPUTE();
        __syncthreads();
        if (s + 1 < 24) {
            SS_WRITE();
            __syncthreads();
        }
    }
#undef SS_ISSUE
#undef SS_WRITE
#undef SS_COMPUTE

    // softmax per row r: row i_loc = wave*16 + quad*4 + r, cols nf*16+l16.
    const float g = 1.0f / (1.0f + __expf(-gate[0]));
    const float gs = (dir == 0) ? g : (1.0f - g);
    unsigned short* Pg = P + (((size_t)dir * 64 + bn) << 14);

    #pragma unroll
    for (int r = 0; r < 4; ++r) {
        const int i_loc = (wave << 4) + (quad << 2) + r;
        const float rqs = rqv[i_loc];
        float v[8], m = -1e30f;
        #pragma unroll
        for (int nf = 0; nf < 8; ++nf) {
            v[nf] = acc[nf][r] * rqs * rkv[(nf << 4) + l16];
            m = fmaxf(m, v[nf]);
        }
        #pragma unroll
        for (int off = 1; off < 16; off <<= 1) m = fmaxf(m, __shfl_xor(m, off));
        float s = 0.0f;
        #pragma unroll
        for (int nf = 0; nf < 8; ++nf) { v[nf] = __expf(v[nf] - m); s += v[nf]; }
        #pragma unroll
        for (int off = 1; off < 16; off <<= 1) s += __shfl_xor(s, off);
        const float inv = gs / s;
        const size_t rowo = (size_t)(i0 + i_loc) * 128;
        #pragma unroll
        for (int nf = 0; nf < 8; ++nf)
            Pg[rowo + (nf << 4) + l16] = f2bf(v[nf] * inv);
    }
}

// ---------------------------------------------------------------------------
// pv: per (ch, bn) plane, F = P1g@A1 + A2@P2g^T + g*rq1[h]*A2 + (1-g)*rq2[w]*A1.
// All inputs bf16 (P carries gate factors). A1^T tile read directly from o1T.
// grid (24 ch, 64 bn), block 256.
// ---------------------------------------------------------------------------
__global__ __launch_bounds__(256)
void pv_mfma(const unsigned short* __restrict__ o1, const unsigned short* __restrict__ o2,
             const unsigned short* __restrict__ o1T,
             const unsigned short* __restrict__ P, const float* __restrict__ norms,
             const float* __restrict__ gate, unsigned short* __restrict__ fusion)
{
    __shared__ unsigned short P1s[128][40];
    __shared__ unsigned short A2s[128][40];
    __shared__ unsigned short P2s[128][40];
    __shared__ unsigned short A1Ts[128][40];
    __shared__ float rqs[256];

    const int tid = threadIdx.x;
    const int ch  = blockIdx.x;
    const int bn  = blockIdx.y;
    const int b = bn >> 3, n = bn & 7;

    const size_t pbase = (size_t)b * C_DIM * N_PIX + ((size_t)n * C_PH + ch) * N_PIX;
    const unsigned short* A1  = o1 + pbase;
    const unsigned short* A2  = o2 + pbase;
    const unsigned short* A1T = o1T + pbase;
    const unsigned short* P1 = P + ((size_t)bn << 14);
    const unsigned short* P2 = P + ((size_t)(64 + bn) << 14);
    unsigned short* Fp = fusion + pbase;

    const float g = 1.0f / (1.0f + __expf(-gate[0]));
    if (tid < 128)
        rqs[tid] = g * rsqrtf(fmaxf(norms[(((size_t)8 + b) * 8 + n) * 256 + tid], 1e-24f));
    else
        rqs[tid] = (1.0f - g) * rsqrtf(fmaxf(norms[(((size_t)b) * 8 + n) * 256 + 128 + (tid - 128)], 1e-24f));

    const int wave = tid >> 6, lane = tid & 63;
    const int quad = lane >> 4, l16 = lane & 15;
    const int i0w = wave << 5;
    const int koff = quad << 3;

    f32x4 acc[2][8];
    #pragma unroll
    for (int i = 0; i < 2; ++i)
        #pragma unroll
        for (int j = 0; j < 8; ++j) acc[i][j] = (f32x4){0.f, 0.f, 0.f, 0.f};

    for (int k0 = 0; k0 < 128; k0 += 32) {
        // all four tiles are natural row-major uint4 copies now
        #pragma unroll
        for (int r = 0; r < 2; ++r) {
            const int u = tid + (r << 8);
            const int row = u >> 2, k8 = u & 3;
            const size_t go = (size_t)row * 128 + k0 + (k8 << 3);
            *(uint4*)(&P1s[row][k8 << 3])  = *(const uint4*)(P1 + go);
            *(uint4*)(&A2s[row][k8 << 3])  = *(const uint4*)(A2 + go);
            *(uint4*)(&P2s[row][k8 << 3])  = *(const uint4*)(P2 + go);
            *(uint4*)(&A1Ts[row][k8 << 3]) = *(const uint4*)(A1T + go);
        }
        __syncthreads();

        bf16x8 p1f[2], a2f[2];
        #pragma unroll
        for (int mf = 0; mf < 2; ++mf) {
            p1f[mf] = *(const bf16x8*)(&P1s[i0w + (mf << 4) + l16][koff]);
            a2f[mf] = *(const bf16x8*)(&A2s[i0w + (mf << 4) + l16][koff]);
        }
        #pragma unroll
        for (int nf = 0; nf < 8; ++nf) {
            const bf16x8 b1 = *(const bf16x8*)(&A1Ts[(nf << 4) + l16][koff]);
            const bf16x8 b2 = *(const bf16x8*)(&P2s[(nf << 4) + l16][koff]);
            #pragma unroll
            for (int mf = 0; mf < 2; ++mf) {
                acc[mf][nf] = __builtin_amdgcn_mfma_f32_16x16x32_bf16(p1f[mf], b1, acc[mf][nf], 0, 0, 0);
                acc[mf][nf] = __builtin_amdgcn_mfma_f32_16x16x32_bf16(a2f[mf], b2, acc[mf][nf], 0, 0, 0);
            }
        }
        __syncthreads();
    }

    #pragma unroll
    for (int mf = 0; mf < 2; ++mf) {
        #pragma unroll
        for (int r = 0; r < 4; ++r) {
            const int i = i0w + (mf << 4) + (quad << 2) + r;
            const float c1 = rqs[i];
            #pragma unroll
            for (int nf = 0; nf < 8; ++nf) {
                const int w = (nf << 4) + l16;
                const size_t o = (size_t)i * 128 + w;
                const float F = acc[mf][nf][r] + c1 * bf2f(A2[o]) + rqs[128 + w] * bf2f(A1[o]);
                Fp[o] = f2bf(F);
            }
        }
    }
}

// ---------------------------------------------------------------------------
extern "C" void kernel_launch(void* const* d_in, const int* in_sizes, int n_in,
                              void* d_out, int out_size, void* d_ws, size_t ws_size,
                              hipStream_t stream)
{
    (void)in_sizes; (void)n_in; (void)out_size; (void)ws_size;
    const float* x1     = (const float*)d_in[0];
    const float* x2     = (const float*)d_in[1];
    const float* W_proj = (const float*)d_in[2];
    const float* b_proj = (const float*)d_in[3];
    const float* gate   = (const float*)d_in[4];
    // d_in[5], d_in[6]: pos_bias_h/w — per-head scalars, cancel in softmax.
    const float* W_m1   = (const float*)d_in[7];
    const float* b_m1   = (const float*)d_in[8];
    const float* W_m2   = (const float*)d_in[9];
    const float* b_m2   = (const float*)d_in[10];

    unsigned short* o1    = (unsigned short*)d_ws;       // out1 bf16
    unsigned short* o2    = o1 + ELEMS;                  // out2 bf16
    float*          norms = (float*)(o2 + ELEMS);        // 32768 f32
    unsigned short* Pbuf  = (unsigned short*)(norms + 32768);  // 2*64*16384 bf16

    // d_out aliasing: [o2T (dead before pv) -> fusion][o1T (dead before conv7)]
    unsigned short* o2T    = (unsigned short*)d_out;
    unsigned short* fusion = o2T;
    unsigned short* o1T    = o2T + ELEMS;

    const dim3 cgrid(64, 3, 8);
    conv_f32in<<<cgrid, 256, 0, stream>>>(x1, W_proj, b_proj, o1);
    conv_f32in<<<cgrid, 256, 0, stream>>>(x2, W_proj, b_proj, o2);

    hipMemsetAsync(norms, 0, 32768 * sizeof(float), stream);
    transpose_norms<<<dim3(192, 8, 2), 256, 0, stream>>>(o1, o2, o1T, o2T, norms);

    scores_softmax<<<dim3(64, 2, 2), 256, 0, stream>>>(o1, o2, o1T, o2T, norms, gate, Pbuf);
    pv_mfma<<<dim3(24, 64), 256, 0, stream>>>(o1, o2, o1T, Pbuf, norms, gate, fusion);

    conv_b16in<0><<<cgrid, 256, 0, stream>>>(fusion, W_proj, b_proj, o1, nullptr, nullptr);
    conv_b16in<1><<<cgrid, 256, 0, stream>>>(o1, W_m1, b_m1, o2, nullptr, nullptr);
    conv_b16in<2><<<cgrid, 256, 0, stream>>>(o2, W_m2, b_m2, d_out, x1, x2);
}